// Round 9
// baseline (375.811 us; speedup 1.0000x reference)
//
#include <hip/hip_runtime.h>

// Causal single-head attention, B=8, N=2048, D=1024, fp32 in/out, bf16 MFMA compute.
//
// Round-8 lesson: the round-6 E/PV changes (XCD-compact E grid + atomic rowsum,
// 256-block two-pass PV) regressed E+PV from ~160 us (round 4, measured) to ~215 us:
// E's per-XCD 4 MiB L2 can't hold a batch's Q+K panels (8 MiB) -> FETCH 103->157 MB;
// PV at 1 block/CU halved wave occupancy. This version REVERTS E and PV to the
// round-4 measured-good forms and KEEPS the fused QKV (measured good: 3x66 -> 120 us).
//
// Pipeline (4 launches on `stream`):
//   1. cast_f32_bf16:      x (fp32) -> xb (bf16)
//   2. transpose_cast_w3:  Wq/Wk/Wv (fp32 KxN) -> [WqT|WkT|WvT] (bf16 3072x1024)
//   3. gemm128<4>: fused QKV: [Q|K|V] = xb·[Wq|Wk|Wv]; Q,K row-major; V transposed (Vt)
//   4. gemm128<2>: E = exp(scale·Q·K^T) bf16, causal, lower tiles only (spread 3D grid)
//   5. gemm128<3>: out = (E·V)/rowsum(E); 512 blocks, heavy-first, in-loop rowsum
//
// gemm128 core (proven rounds 4-8): 128x256 tile, 512 thr (8 waves = 2M x 4N, wave
// tile 64x64), BK=32, 3-stage LDS ring (72 KiB -> 2 blocks/CU), ONE barrier per
// K-tile, counted vmcnt(3) (next prefetched tile stays in flight across the barrier),
// XOR-swizzled LDS reads via pre-swizzled global source, setprio on the MFMA cluster.
// Ring safety: iter t reads buf t%3 (iter t-1's VWAIT(3) left only tile t+1's loads
// in flight, so tile t landed). STAGE(t+2) targets buf (t-1)%3 whose readers retired
// before the iter t-1 barrier (explicit lgkmcnt(0)).

typedef unsigned short u16;
typedef __bf16 bf16x8 __attribute__((ext_vector_type(8)));
typedef float f32x4 __attribute__((ext_vector_type(4)));
typedef unsigned short u16x8 __attribute__((ext_vector_type(8)));
typedef unsigned short u16x4 __attribute__((ext_vector_type(4)));

static constexpr int BATCH = 8;
static constexpr int SEQ = 2048;
static constexpr int DIM = 1024;

static constexpr size_t SZ_XB = (size_t)BATCH * SEQ * DIM * 2;  // 32 MiB
static constexpr size_t SZ_W  = (size_t)DIM * DIM * 2;          // 2 MiB
static constexpr size_t OFF_XB  = 0;
static constexpr size_t OFF_WQT = OFF_XB + SZ_XB;   // [WqT|WkT|WvT] contiguous: 3072x1024
static constexpr size_t OFF_Q   = OFF_WQT + 3 * SZ_W;
static constexpr size_t OFF_K   = OFF_Q + SZ_XB;
static constexpr size_t OFF_VT  = OFF_K + SZ_XB;
static constexpr size_t OFF_E   = OFF_VT + SZ_XB;   // bf16 8x2048x2048 = 64 MiB

__device__ __forceinline__ u16 f2b(float f) {
  unsigned u = __builtin_bit_cast(unsigned, f);
  u += 0x7fffu + ((u >> 16) & 1u);
  return (u16)(u >> 16);
}

__device__ __forceinline__ void gload16(const u16* g, u16* l) {
  __builtin_amdgcn_global_load_lds((__attribute__((address_space(1))) void*)g,
                                   (__attribute__((address_space(3))) void*)l, 16, 0, 0);
}

#define VWAIT(N) asm volatile("s_waitcnt vmcnt(" #N ")" ::: "memory")

__device__ __forceinline__ void barrier_raw() {
  __builtin_amdgcn_sched_barrier(0);
  __builtin_amdgcn_s_barrier();
  __builtin_amdgcn_sched_barrier(0);
}

__global__ __launch_bounds__(256) void cast_f32_bf16(const float* __restrict__ in,
                                                     u16* __restrict__ out) {
  const size_t i = ((size_t)blockIdx.x * 256 + threadIdx.x) * 8;
  float4 a = *(const float4*)(in + i);
  float4 b = *(const float4*)(in + i + 4);
  u16x8 o;
  o[0] = f2b(a.x); o[1] = f2b(a.y); o[2] = f2b(a.z); o[3] = f2b(a.w);
  o[4] = f2b(b.x); o[5] = f2b(b.y); o[6] = f2b(b.z); o[7] = f2b(b.w);
  *reinterpret_cast<u16x8*>(out + i) = o;
}

__global__ __launch_bounds__(256) void transpose_cast_w3(const float* __restrict__ W0,
                                                         const float* __restrict__ W1,
                                                         const float* __restrict__ W2,
                                                         u16* __restrict__ WT) {
  __shared__ float t[32][33];
  const float* W = (blockIdx.z == 0) ? W0 : (blockIdx.z == 1) ? W1 : W2;
  u16* dst = WT + (size_t)blockIdx.z * DIM * DIM;
  const int k0 = blockIdx.x * 32, n0 = blockIdx.y * 32;
  const int tx = threadIdx.x, ty = threadIdx.y;
#pragma unroll
  for (int dy = 0; dy < 32; dy += 8)
    t[ty + dy][tx] = W[(size_t)(k0 + ty + dy) * DIM + n0 + tx];
  __syncthreads();
#pragma unroll
  for (int dy = 0; dy < 32; dy += 8)
    dst[(size_t)(n0 + ty + dy) * DIM + k0 + tx] = f2b(t[tx][ty + dy]);
}

// ---------------------------------------------------------------------------
// gemm128<MODE>: C = A(bf16 MxK rm) * Bt(bf16 NxK rm)^T, 128x256 tile.
// MODE 4: fused QKV (1D grid, XCD-chunk swizzled). Bt = [WqT|WkT|WvT] (3072x1024).
//         colTile>>10 selects dest: 0 -> C (=Q) rm; 1 -> C2 (=K) rm; 2 -> C3 (=Vt)
//         transposed per batch: Vt[b][d][n], b=row>>11, n=row&2047.
// MODE 2: C bf16 = exp(acc*scale) causal-masked; 3D spread grid, tiles with
//         2*bx > by return early (before any barrier). No rowsum side-channel.
// MODE 3: C fp32 = acc / rowsum(A-row); K limited to (by+1)*128; by reversed so
//         heavy tiles dispatch first; rowsum accumulated in-loop from A-fragments.
//
// LDS swizzle: logical [rows][32] bf16 (64B rows). Read of (row, quad) is 16B at
//   byte ((row*64 + quad*16) ^ (((row>>1)&7)<<4)).
// global_load_lds writes linearly (chunk c -> byte c*16), so the per-lane GLOBAL
// source for chunk c is the inverse image:  P=c>>3, u=(c&7)^(P&7),
//   row = 2P + (u>>2), kchunk = u&3.   (Verified: swz(row,kchunk) == c*16.)
// ---------------------------------------------------------------------------
template <int MODE>
__global__ __launch_bounds__(512, 4) void gemm128(
    const u16* __restrict__ A, size_t sA, int lda,
    const u16* __restrict__ Bt, size_t sB, int ldb,
    void* __restrict__ C, size_t sC, int ldc,
    int Kdim, float scale,
    void* __restrict__ C2, void* __restrict__ C3) {
  const int tid = threadIdx.x;

  int bx, by, bz;
  if (MODE == 4) {
    const int o = (int)blockIdx.x;            // 0..1535
    const int nw = (o & 7) * 192 + (o >> 3);  // XCD k: by in [16k,16k+16) = 4 MiB A-panels
    bx = nw % 12; by = nw / 12; bz = 0;
  } else {
    bx = (int)blockIdx.x;
    bz = (int)blockIdx.z;
    by = (MODE == 3) ? (int)(gridDim.y - 1 - blockIdx.y) : (int)blockIdx.y;
    if (MODE == 2 && 2 * bx > by) return;  // uniform early-out, before any barrier
  }

  const u16* Ab = A + (size_t)bz * sA;
  const u16* Bb = Bt + (size_t)bz * sB;
  const int rowTile = by * 128, colTile = bx * 256;
  int kmax = Kdim;
  if (MODE == 3) {
    int km = (by + 1) * 128;
    if (km < kmax) kmax = km;
  }
  const int NT = kmax >> 5;  // BK=32; NT >= 4 always

  __shared__ __align__(16) u16 lds[3 * 12288];  // 3 stages x (A 8KB + B 16KB) = 72 KiB

  const int w = tid >> 6, l = tid & 63;
  const int wm = w >> 2, wn = w & 3;  // 2 x 4 wave grid; wave owns 64x64 of C
  const int lr = l & 15, quad = l >> 4;

  // staging source lane mapping (inverse swizzle)
  auto srow = [](int c) { int u = (c & 7) ^ ((c >> 3) & 7); return 2 * (c >> 3) + (u >> 2); };
  auto skq  = [](int c) { int u = (c & 7) ^ ((c >> 3) & 7); return u & 3; };
  const int srA = srow(tid), skA = skq(tid);
  const u16* pA0 = Ab + (size_t)(rowTile + srA) * lda + skA * 8;                         // rows 0..127
  const u16* pB0 = Bb + (size_t)(colTile + srA) * ldb + skA * 8;                         // rows 0..127
  const u16* pB1 = Bb + (size_t)(colTile + srow(tid + 512)) * ldb + skq(tid + 512) * 8;  // 128..255

  // swizzled LDS read offsets (u16 units, 16B aligned); A region [0,4096), B [4096,12288)
  int offA[4], offB[4];
#pragma unroll
  for (int mi = 0; mi < 4; ++mi) {
    const int row = wm * 64 + mi * 16 + lr;
    offA[mi] = ((row * 64 + quad * 16) ^ (((row >> 1) & 7) << 4)) >> 1;
  }
#pragma unroll
  for (int ni = 0; ni < 4; ++ni) {
    const int row = wn * 64 + ni * 16 + lr;
    offB[ni] = 4096 + ((((row * 64 + quad * 16) ^ (((row >> 1) & 7) << 4))) >> 1);
  }

  f32x4 acc[4][4];
#pragma unroll
  for (int i = 0; i < 4; ++i)
#pragma unroll
    for (int j = 0; j < 4; ++j) acc[i][j] = (f32x4){0.f, 0.f, 0.f, 0.f};
  float rsum[4] = {0.f, 0.f, 0.f, 0.f};  // MODE 3: per-lane partial row sums of A

#define STAGE(tt)                                   \
  {                                                 \
    u16* sb = &lds[((unsigned)(tt) % 3u) * 12288];  \
    const int ko = (tt) * 32;                       \
    gload16(pA0 + ko, sb + w * 512);                \
    gload16(pB0 + ko, sb + 4096 + w * 512);         \
    gload16(pB1 + ko, sb + 8192 + w * 512);         \
  }

  // prologue: stage tiles 0,1 (6 loads/wave); require tile 0 landed, tile 1 in flight
  STAGE(0);
  STAGE(1);
  VWAIT(3);
  barrier_raw();

  for (int t = 0; t < NT; ++t) {
    const u16* S = &lds[((unsigned)t % 3u) * 12288];
    bf16x8 af[4], bf[4];
#pragma unroll
    for (int mi = 0; mi < 4; ++mi)
      af[mi] = *reinterpret_cast<const bf16x8*>(&S[offA[mi]]);
#pragma unroll
    for (int ni = 0; ni < 4; ++ni)
      bf[ni] = *reinterpret_cast<const bf16x8*>(&S[offB[ni]]);
    if (t + 2 < NT) STAGE(t + 2);  // buf (t+2)%3 == (t-1)%3: readers retired at t-1 barrier
    if (MODE == 3) {
#pragma unroll
      for (int mi = 0; mi < 4; ++mi) {
        float s = 0.f;
#pragma unroll
        for (int j = 0; j < 8; ++j) s += (float)af[mi][j];
        rsum[mi] += s;
      }
    }
    __builtin_amdgcn_s_setprio(1);
#pragma unroll
    for (int mi = 0; mi < 4; ++mi)
#pragma unroll
      for (int ni = 0; ni < 4; ++ni)
        acc[mi][ni] =
            __builtin_amdgcn_mfma_f32_16x16x32_bf16(af[mi], bf[ni], acc[mi][ni], 0, 0, 0);
    __builtin_amdgcn_s_setprio(0);
    // counted wait: tile t+1 must land before next iter's reads; t+2 stays in flight
    if (t + 2 < NT) {
      VWAIT(3);
    } else if (t + 1 < NT) {
      VWAIT(0);
    }
    asm volatile("s_waitcnt lgkmcnt(0)" ::: "memory");  // ds_reads retired before reuse
    barrier_raw();
  }
#undef STAGE

  if (MODE == 3) {
    // finish row sums: lanes {lr, lr+16, lr+32, lr+48} hold quad-partials
#pragma unroll
    for (int mi = 0; mi < 4; ++mi) {
      rsum[mi] += __shfl_xor(rsum[mi], 16);
      rsum[mi] += __shfl_xor(rsum[mi], 32);
    }
  }

  // ---- epilogue ----  C/D layout: col = lane&15, row = (lane>>4)*4 + reg [m89]
  const int orow0 = rowTile + wm * 64 + quad * 4;
  const int ocol0 = colTile + wn * 64 + lr;

  if (MODE == 4) {
    const int which = colTile >> 10;  // 0=Q, 1=K, 2=V (block-uniform)
    const int colL0 = ocol0 & 1023;
    if (which < 2) {
      u16* dst = (which == 0) ? (u16*)C : (u16*)C2;
#pragma unroll
      for (int mi = 0; mi < 4; ++mi)
#pragma unroll
        for (int ni = 0; ni < 4; ++ni) {
          const int colg = colL0 + ni * 16;
#pragma unroll
          for (int r = 0; r < 4; ++r) {
            const int rowg = orow0 + mi * 16 + r;
            dst[(size_t)rowg * DIM + colg] = f2b(acc[mi][ni][r]);
          }
        }
    } else {
      u16* dst = (u16*)C3;  // Vt[b][d][n]
#pragma unroll
      for (int mi = 0; mi < 4; ++mi) {
        const int rowg0 = orow0 + mi * 16;  // multiple of 4; no 2048-boundary cross
        const int bb = rowg0 >> 11, nn = rowg0 & (SEQ - 1);
#pragma unroll
        for (int ni = 0; ni < 4; ++ni) {
          const int colg = colL0 + ni * 16;
          u16x4 pk;
#pragma unroll
          for (int r = 0; r < 4; ++r) pk[r] = f2b(acc[mi][ni][r]);
          *reinterpret_cast<u16x4*>(
              &dst[(size_t)bb * ((size_t)DIM * SEQ) + (size_t)colg * SEQ + nn]) = pk;
        }
      }
    }
  } else if (MODE == 2) {
#pragma unroll
    for (int mi = 0; mi < 4; ++mi)
#pragma unroll
      for (int ni = 0; ni < 4; ++ni) {
        const int colg = ocol0 + ni * 16;
#pragma unroll
        for (int r = 0; r < 4; ++r) {
          const int rowg = orow0 + mi * 16 + r;
          const float e = (colg <= rowg) ? __expf(acc[mi][ni][r] * scale) : 0.f;
          ((u16*)C)[(size_t)bz * sC + (size_t)rowg * ldc + colg] = f2b(e);
        }
      }
  } else {  // MODE 3
#pragma unroll
    for (int mi = 0; mi < 4; ++mi) {
      float linv[4];
#pragma unroll
      for (int r = 0; r < 4; ++r) linv[r] = 1.f / __shfl(rsum[mi], quad * 4 + r);
#pragma unroll
      for (int ni = 0; ni < 4; ++ni) {
        const int colg = ocol0 + ni * 16;
#pragma unroll
        for (int r = 0; r < 4; ++r) {
          const int rowg = orow0 + mi * 16 + r;
          ((float*)C)[(size_t)bz * sC + (size_t)rowg * ldc + colg] =
              acc[mi][ni][r] * linv[r];
        }
      }
    }
  }
}

extern "C" void kernel_launch(void* const* d_in, const int* in_sizes, int n_in,
                              void* d_out, int out_size, void* d_ws, size_t ws_size,
                              hipStream_t stream) {
  const float* x = (const float*)d_in[0];
  const float* Wq = (const float*)d_in[1];
  const float* Wk = (const float*)d_in[2];
  const float* Wv = (const float*)d_in[3];
  float* out = (float*)d_out;
  char* ws = (char*)d_ws;

  u16* xb = (u16*)(ws + OFF_XB);
  u16* wT = (u16*)(ws + OFF_WQT);  // [WqT|WkT|WvT] contiguous: 3072 x 1024
  u16* qb = (u16*)(ws + OFF_Q);
  u16* kb = (u16*)(ws + OFF_K);
  u16* vt = (u16*)(ws + OFF_VT);
  u16* eb = (u16*)(ws + OFF_E);

  const int total = BATCH * SEQ * DIM;
  cast_f32_bf16<<<total / (256 * 8), 256, 0, stream>>>(x, xb);
  transpose_cast_w3<<<dim3(32, 32, 3), dim3(32, 8), 0, stream>>>(Wq, Wk, Wv, wT);

  // Fused QKV: [Q|K|V] = xb · [Wq|Wk|Wv]  (M=16384, N=3072, K=1024); 1536 blocks
  gemm128<4><<<1536, 512, 0, stream>>>(
      xb, 0, DIM, wT, 0, DIM, qb, 0, DIM, DIM, 1.f, kb, vt);
  // E = exp(scale·Q·K^T), causal, bf16; spread 3D grid (round-4 form, FETCH-friendly)
  gemm128<2><<<dim3(8, 16, BATCH), 512, 0, stream>>>(
      qb, (size_t)SEQ * DIM, DIM, kb, (size_t)SEQ * DIM, DIM, eb, (size_t)SEQ * SEQ, SEQ,
      DIM, 0.03125f, nullptr, nullptr);
  // out = (E·V)/rowsum via Vt; 512 blocks, heavy-first, in-loop rowsum (round-4 form)
  gemm128<3><<<dim3(4, 16, BATCH), 512, 0, stream>>>(
      eb, (size_t)SEQ * SEQ, SEQ, vt, (size_t)DIM * SEQ, SEQ, out, (size_t)SEQ * DIM, DIM,
      SEQ, 1.f, nullptr, nullptr);
}

// Round 10
// 356.833 us; speedup vs baseline: 1.0532x; 1.0532x over previous
//
#include <hip/hip_runtime.h>

// Causal single-head attention, B=8, N=2048, D=1024, fp32 in/out, bf16 MFMA compute.
//
// Base = round-8 config (best measured, 363.0 us), with ONE structural change:
// the fused-QKV gemm is re-tiled 128x256 -> 256x256 with wave tile 128x64.
// Round-8/9 counters: QKV = 120 us, MfmaUtil 37%, conflicts 0 — the K-loop is
// LDS-read limited (8 ds_read_b128 per 16 MFMA = 512 B/MFMA). Wave tile 128x64
// gives 12 ds_read_b128 per 32 MFMA = 384 B/MFMA (-25% LDS traffic), and with
// BK=32 + a 2-slab double buffer the LDS stays 64 KiB -> 2 blocks/CU remain
// resident (the TLP that beat the round-1 four-slab 256^2 attempt).
//
// Pipeline (4 launches on `stream`):
//   1. prep:      cast x->xb (bf16), transpose Wq/Wk/Wv -> [WqT|WkT|WvT], zero rs[]
//   2. qkv256:    [Q|K|V] = xb·[Wq|Wk|Wv]; Q,K row-major; V transposed (Vt)
//   3. gemm128<2>: E = exp(scale·Q·K^T) bf16, causal; compact triangle grid (576);
//      epilogue accumulates per-row sums of bf16-rounded E into rs[] (atomicAdd)
//   4. gemm128<3>: out = (E·V) * (1/rs[row]); 256 uniform two-pass blocks
//      (by = 15-by0 heavy then by0 light -> exactly 17*128 K-steps per block)
//
// qkv256 schedule (provable, same discipline as the proven 3-ring):
//   QSTAGE(0); for t: { if t+1<NT {QSTAGE(t+1); VWAIT(4);} else VWAIT(0);
//                       barrier; ds_read af[8],bf[4]; 32 MFMA; lgkmcnt(0); barrier; }
//   Data:  VWAIT(4) leaves only tile t+1's 4 loads in flight -> tile t landed;
//          barrier makes that true for ALL waves' loads.
//   WAR:   QSTAGE(t+1) overwrites buf ~cur, whose readers (iter t-1) retired their
//          ds_reads at iter t-1's lgkmcnt(0) before its barrier, which the stager
//          passed before issuing.

typedef unsigned short u16;
typedef __bf16 bf16x8 __attribute__((ext_vector_type(8)));
typedef float f32x4 __attribute__((ext_vector_type(4)));
typedef unsigned short u16x8 __attribute__((ext_vector_type(8)));
typedef unsigned short u16x4 __attribute__((ext_vector_type(4)));

static constexpr int BATCH = 8;
static constexpr int SEQ = 2048;
static constexpr int DIM = 1024;

static constexpr size_t SZ_XB = (size_t)BATCH * SEQ * DIM * 2;  // 32 MiB
static constexpr size_t SZ_W  = (size_t)DIM * DIM * 2;          // 2 MiB
static constexpr size_t OFF_XB  = 0;
static constexpr size_t OFF_WQT = OFF_XB + SZ_XB;   // [WqT|WkT|WvT] contiguous: 3072x1024
static constexpr size_t OFF_Q   = OFF_WQT + 3 * SZ_W;
static constexpr size_t OFF_K   = OFF_Q + SZ_XB;
static constexpr size_t OFF_VT  = OFF_K + SZ_XB;
static constexpr size_t OFF_E   = OFF_VT + SZ_XB;   // bf16 8x2048x2048 = 64 MiB
static constexpr size_t OFF_RS  = OFF_E + (size_t)BATCH * SEQ * SEQ * 2;  // f32 8x2048

__device__ __forceinline__ u16 f2b(float f) {
  unsigned u = __builtin_bit_cast(unsigned, f);
  u += 0x7fffu + ((u >> 16) & 1u);
  return (u16)(u >> 16);
}

__device__ __forceinline__ float b2f(u16 b) {
  return __builtin_bit_cast(float, ((unsigned)b) << 16);
}

__device__ __forceinline__ void gload16(const u16* g, u16* l) {
  __builtin_amdgcn_global_load_lds((__attribute__((address_space(1))) void*)g,
                                   (__attribute__((address_space(3))) void*)l, 16, 0, 0);
}

#define VWAIT(N) asm volatile("s_waitcnt vmcnt(" #N ")" ::: "memory")

__device__ __forceinline__ void barrier_raw() {
  __builtin_amdgcn_sched_barrier(0);
  __builtin_amdgcn_s_barrier();
  __builtin_amdgcn_sched_barrier(0);
}

// ---------------------------------------------------------------------------
// prep: blocks 0..8191 cast x -> xb (bf16x8 per thread); block 0 also zeroes rs.
//       blocks 8192..11263: 32x32 transpose-cast of Wq/Wk/Wv into WT.
// ---------------------------------------------------------------------------
__global__ __launch_bounds__(256) void prep(const float* __restrict__ x,
                                            u16* __restrict__ xb,
                                            const float* __restrict__ W0,
                                            const float* __restrict__ W1,
                                            const float* __restrict__ W2,
                                            u16* __restrict__ WT,
                                            float* __restrict__ rs) {
  const int b = blockIdx.x;
  if (b < 8192) {
    const size_t i = ((size_t)b * 256 + threadIdx.x) * 8;
    float4 a = *(const float4*)(x + i);
    float4 c = *(const float4*)(x + i + 4);
    u16x8 o;
    o[0] = f2b(a.x); o[1] = f2b(a.y); o[2] = f2b(a.z); o[3] = f2b(a.w);
    o[4] = f2b(c.x); o[5] = f2b(c.y); o[6] = f2b(c.z); o[7] = f2b(c.w);
    *reinterpret_cast<u16x8*>(xb + i) = o;
    if (b == 0) {
      for (int j = threadIdx.x; j < BATCH * SEQ; j += 256) rs[j] = 0.f;
    }
  } else {
    __shared__ float t[32][33];
    const int bb = b - 8192;
    const int z = bb >> 10, rem = bb & 1023;
    const int k0 = (rem & 31) * 32, n0 = (rem >> 5) * 32;
    const float* W = (z == 0) ? W0 : (z == 1) ? W1 : W2;
    u16* dst = WT + (size_t)z * DIM * DIM;
    const int tx = threadIdx.x & 31, ty = threadIdx.x >> 5;
#pragma unroll
    for (int dy = 0; dy < 32; dy += 8)
      t[ty + dy][tx] = W[(size_t)(k0 + ty + dy) * DIM + n0 + tx];
    __syncthreads();
#pragma unroll
    for (int dy = 0; dy < 32; dy += 8)
      dst[(size_t)(n0 + ty + dy) * DIM + k0 + tx] = f2b(t[tx][ty + dy]);
  }
}

// ---------------------------------------------------------------------------
// qkv256: [Q|K|V] = xb(16384x1024) · WT(3072x1024)^T, 256x256 tiles, 512 thr,
// 8 waves = 2M x 4N (wave tile 128x64), BK=32, 2-slab double buffer (64 KiB ->
// 2 blocks/CU), counted VWAIT(4), XOR-swizzled LDS reads via pre-swizzled
// global source, setprio around the 32-MFMA cluster.
// Grid 768 = 64 by x 12 bx, XCD-chunk swizzled (by-panels per XCD = 4 MiB = L2).
// Epilogue: bx>>2 selects 0=Q rm, 1=K rm, 2=Vt[b][d][n] (u16x4 stores).
// ---------------------------------------------------------------------------
__global__ __launch_bounds__(512, 2) void qkv256(const u16* __restrict__ A,
                                                 const u16* __restrict__ Bt,
                                                 u16* __restrict__ Q,
                                                 u16* __restrict__ Kb,
                                                 u16* __restrict__ Vt) {
  const int tid = threadIdx.x;
  const int o = (int)blockIdx.x;           // 0..767
  const int nw = (o & 7) * 96 + (o >> 3);  // bijective XCD chunk (768 = 8*96)
  const int bx = nw % 12, by = nw / 12;    // by 0..63
  const int rowTile = by * 256, colTile = bx * 256;
  constexpr int NT = 32;  // K = 1024, BK = 32

  __shared__ __align__(16) u16 lds[2 * 16384];  // 2 slabs x (A 16KB + B 16KB) = 64 KiB

  const int w = tid >> 6, l = tid & 63;
  const int wm = w >> 2, wn = w & 3;  // wave tile 128x64
  const int lr = l & 15, quad = l >> 4;

  // staging source lane mapping (inverse of the read swizzle; verified in round 1/2)
  auto srow = [](int c) { int u = (c & 7) ^ ((c >> 3) & 7); return 2 * (c >> 3) + (u >> 2); };
  auto skq  = [](int c) { int u = (c & 7) ^ ((c >> 3) & 7); return u & 3; };
  const u16* pA0 = A + (size_t)(rowTile + srow(tid)) * DIM + skq(tid) * 8;
  const u16* pA1 = A + (size_t)(rowTile + srow(tid + 512)) * DIM + skq(tid + 512) * 8;
  const u16* pB0 = Bt + (size_t)(colTile + srow(tid)) * DIM + skq(tid) * 8;         // rows <= 3071
  const u16* pB1 = Bt + (size_t)(colTile + srow(tid + 512)) * DIM + skq(tid + 512) * 8;

  // swizzled LDS read offsets (u16 units); A region [0,8192), B region [8192,16384)
  int offA[8], offB[4];
#pragma unroll
  for (int mi = 0; mi < 8; ++mi) {
    const int row = wm * 128 + mi * 16 + lr;
    offA[mi] = ((row * 64 + quad * 16) ^ (((row >> 1) & 7) << 4)) >> 1;
  }
#pragma unroll
  for (int ni = 0; ni < 4; ++ni) {
    const int row = wn * 64 + ni * 16 + lr;
    offB[ni] = 8192 + ((((row * 64 + quad * 16) ^ (((row >> 1) & 7) << 4))) >> 1);
  }

  f32x4 acc[8][4];
#pragma unroll
  for (int i = 0; i < 8; ++i)
#pragma unroll
    for (int j = 0; j < 4; ++j) acc[i][j] = (f32x4){0.f, 0.f, 0.f, 0.f};

#define QSTAGE(tt)                              \
  {                                             \
    u16* sb = &lds[((tt) & 1) * 16384];         \
    const int ko = (tt) * 32;                   \
    gload16(pA0 + ko, sb + w * 512);            \
    gload16(pA1 + ko, sb + 4096 + w * 512);     \
    gload16(pB0 + ko, sb + 8192 + w * 512);     \
    gload16(pB1 + ko, sb + 12288 + w * 512);    \
  }

  QSTAGE(0);
  for (int t = 0; t < NT; ++t) {
    if (t + 1 < NT) {
      QSTAGE(t + 1);  // buf ~cur: its iter t-1 readers retired before last barrier
      VWAIT(4);       // only tile t+1's 4 loads may remain in flight -> tile t landed
    } else {
      VWAIT(0);
    }
    barrier_raw();    // all waves' tile-t loads landed
    const u16* S = &lds[(t & 1) * 16384];
    bf16x8 af[8], bf[4];
#pragma unroll
    for (int mi = 0; mi < 8; ++mi)
      af[mi] = *reinterpret_cast<const bf16x8*>(&S[offA[mi]]);
#pragma unroll
    for (int ni = 0; ni < 4; ++ni)
      bf[ni] = *reinterpret_cast<const bf16x8*>(&S[offB[ni]]);
    __builtin_amdgcn_s_setprio(1);
#pragma unroll
    for (int mi = 0; mi < 8; ++mi)
#pragma unroll
      for (int ni = 0; ni < 4; ++ni)
        acc[mi][ni] =
            __builtin_amdgcn_mfma_f32_16x16x32_bf16(af[mi], bf[ni], acc[mi][ni], 0, 0, 0);
    __builtin_amdgcn_s_setprio(0);
    asm volatile("s_waitcnt lgkmcnt(0)" ::: "memory");  // ds_reads retired before reuse
    barrier_raw();
  }
#undef QSTAGE

  // epilogue — C/D layout: col = lane&15, row = (lane>>4)*4 + reg  [m89-verified]
  const int which = bx >> 2;  // 0=Q, 1=K, 2=V (block-uniform)
  const int colL0 = (colTile & 1023) + wn * 64 + lr;
  const int orow0 = rowTile + wm * 128 + quad * 4;
  if (which < 2) {
    u16* dst = (which == 0) ? Q : Kb;
#pragma unroll
    for (int mi = 0; mi < 8; ++mi)
#pragma unroll
      for (int ni = 0; ni < 4; ++ni) {
        const int colg = colL0 + ni * 16;
#pragma unroll
        for (int r = 0; r < 4; ++r) {
          const int rowg = orow0 + mi * 16 + r;
          dst[(size_t)rowg * DIM + colg] = f2b(acc[mi][ni][r]);
        }
      }
  } else {
#pragma unroll
    for (int mi = 0; mi < 8; ++mi) {
      const int rowg0 = orow0 + mi * 16;  // multiple of 4; no 2048-boundary cross
      const int bb = rowg0 >> 11, nn = rowg0 & (SEQ - 1);
#pragma unroll
      for (int ni = 0; ni < 4; ++ni) {
        const int colg = colL0 + ni * 16;
        u16x4 pk;
#pragma unroll
        for (int r = 0; r < 4; ++r) pk[r] = f2b(acc[mi][ni][r]);
        *reinterpret_cast<u16x4*>(
            &Vt[(size_t)bb * ((size_t)DIM * SEQ) + (size_t)colg * SEQ + nn]) = pk;
      }
    }
  }
}

// ---------------------------------------------------------------------------
// gemm128<MODE>: C = A(bf16 MxK rm) * Bt(bf16 NxK rm)^T, 128x256 tile, 1D grid.
// MODE 2: C bf16 = exp(acc*scale) causal-masked; compact triangle grid (72 per
//         batch x 8, XCD-chunk). Epilogue atomically adds rounded-E row sums to rs.
// MODE 3: C fp32 = acc * (1/rs[row]); two balanced passes per block (15-by0, by0).
// Core: 3-stage LDS ring (72 KiB -> 2 blocks/CU), one barrier per K-tile,
// counted vmcnt(3), swizzled LDS, setprio.  (Round-8 verbatim.)
// ---------------------------------------------------------------------------
template <int MODE>
__global__ __launch_bounds__(512, 4) void gemm128(
    const u16* __restrict__ A, size_t sA, int lda,
    const u16* __restrict__ Bt, size_t sB, int ldb,
    void* __restrict__ C, size_t sC, int ldc,
    int Kdim, float scale, float* __restrict__ rs) {
  const int tid = threadIdx.x;

  int bx = 0, by = 0, bz = 0, by0 = 0;
  if (MODE == 2) {
    const int o = (int)blockIdx.x;            // 0..575
    const int nw = (o & 7) * 72 + (o >> 3);
    bz = nw / 72;
    int i = nw % 72;                          // triangle index -> (by, bx), 2*bx <= by
    int cum = 0;
#pragma unroll
    for (int y = 0; y < 16; ++y) {
      const int c = (y >> 1) + 1;
      if (i < cum + c) { by = y; bx = i - cum; break; }
      cum += c;
    }
  } else {  // MODE 3
    const int o = (int)blockIdx.x;            // 0..255
    const int nw = (o & 7) * 32 + (o >> 3);
    bz = nw >> 5; by0 = (nw >> 2) & 7; bx = nw & 3;
  }

  const u16* Ab = A + (size_t)bz * sA;
  const u16* Bb = Bt + (size_t)bz * sB;
  const int colTile = bx * 256;

  __shared__ __align__(16) u16 lds[3 * 12288];  // 72 KiB

  const int w = tid >> 6, l = tid & 63;
  const int wm = w >> 2, wn = w & 3;  // 2 x 4 wave grid; wave owns 64x64 of C
  const int lr = l & 15, quad = l >> 4;

  auto srow = [](int c) { int u = (c & 7) ^ ((c >> 3) & 7); return 2 * (c >> 3) + (u >> 2); };
  auto skq  = [](int c) { int u = (c & 7) ^ ((c >> 3) & 7); return u & 3; };
  const int srA = srow(tid), skA = skq(tid);
  const u16* pB0 = Bb + (size_t)(colTile + srA) * ldb + skA * 8;
  const u16* pB1 = Bb + (size_t)(colTile + srow(tid + 512)) * ldb + skq(tid + 512) * 8;

  int offA[4], offB[4];
#pragma unroll
  for (int mi = 0; mi < 4; ++mi) {
    const int row = wm * 64 + mi * 16 + lr;
    offA[mi] = ((row * 64 + quad * 16) ^ (((row >> 1) & 7) << 4)) >> 1;
  }
#pragma unroll
  for (int ni = 0; ni < 4; ++ni) {
    const int row = wn * 64 + ni * 16 + lr;
    offB[ni] = 4096 + ((((row * 64 + quad * 16) ^ (((row >> 1) & 7) << 4))) >> 1);
  }

#define STAGE(tt)                                   \
  {                                                 \
    u16* sb = &lds[((unsigned)(tt) % 3u) * 12288];  \
    const int ko = (tt) * 32;                       \
    gload16(pA0 + ko, sb + w * 512);                \
    gload16(pB0 + ko, sb + 4096 + w * 512);         \
    gload16(pB1 + ko, sb + 8192 + w * 512);         \
  }

  const int npass = (MODE == 3) ? 2 : 1;
  for (int pass = 0; pass < npass; ++pass) {
    const int byp = (MODE == 3) ? (pass == 0 ? 15 - by0 : by0) : by;
    const int rowTile = byp * 128;
    int kmax = Kdim;
    if (MODE == 3) kmax = (byp + 1) * 128;  // causal K-limit
    const int NT = kmax >> 5;

    const u16* pA0 = Ab + (size_t)(rowTile + srA) * lda + skA * 8;

    f32x4 acc[4][4];
#pragma unroll
    for (int i = 0; i < 4; ++i)
#pragma unroll
      for (int j = 0; j < 4; ++j) acc[i][j] = (f32x4){0.f, 0.f, 0.f, 0.f};

    STAGE(0);
    STAGE(1);
    VWAIT(3);
    barrier_raw();

    for (int t = 0; t < NT; ++t) {
      const u16* S = &lds[((unsigned)t % 3u) * 12288];
      bf16x8 af[4], bf[4];
#pragma unroll
      for (int mi = 0; mi < 4; ++mi)
        af[mi] = *reinterpret_cast<const bf16x8*>(&S[offA[mi]]);
#pragma unroll
      for (int ni = 0; ni < 4; ++ni)
        bf[ni] = *reinterpret_cast<const bf16x8*>(&S[offB[ni]]);
      if (t + 2 < NT) STAGE(t + 2);
      __builtin_amdgcn_s_setprio(1);
#pragma unroll
      for (int mi = 0; mi < 4; ++mi)
#pragma unroll
        for (int ni = 0; ni < 4; ++ni)
          acc[mi][ni] =
              __builtin_amdgcn_mfma_f32_16x16x32_bf16(af[mi], bf[ni], acc[mi][ni], 0, 0, 0);
      __builtin_amdgcn_s_setprio(0);
      if (t + 2 < NT) {
        VWAIT(3);
      } else if (t + 1 < NT) {
        VWAIT(0);
      }
      asm volatile("s_waitcnt lgkmcnt(0)" ::: "memory");
      barrier_raw();
    }

    const int orow0 = rowTile + wm * 64 + quad * 4;
    const int ocol0 = colTile + wn * 64 + lr;

    if (MODE == 2) {
#pragma unroll
      for (int mi = 0; mi < 4; ++mi) {
        float rloc[4] = {0.f, 0.f, 0.f, 0.f};
#pragma unroll
        for (int ni = 0; ni < 4; ++ni) {
          const int colg = ocol0 + ni * 16;
#pragma unroll
          for (int r = 0; r < 4; ++r) {
            const int rowg = orow0 + mi * 16 + r;
            const float e = (colg <= rowg) ? __expf(acc[mi][ni][r] * scale) : 0.f;
            const u16 pk = f2b(e);
            ((u16*)C)[(size_t)bz * sC + (size_t)rowg * ldc + colg] = pk;
            rloc[r] += b2f(pk);
          }
        }
#pragma unroll
        for (int r = 0; r < 4; ++r) {
          float v = rloc[r];
          v += __shfl_xor(v, 1);
          v += __shfl_xor(v, 2);
          v += __shfl_xor(v, 4);
          v += __shfl_xor(v, 8);
          if (lr == 0) atomicAdd(&rs[bz * SEQ + orow0 + mi * 16 + r], v);
        }
      }
    } else {  // MODE 3
#pragma unroll
      for (int mi = 0; mi < 4; ++mi) {
        float linv[4];
#pragma unroll
        for (int r = 0; r < 4; ++r) linv[r] = 1.f / rs[bz * SEQ + orow0 + mi * 16 + r];
#pragma unroll
        for (int ni = 0; ni < 4; ++ni) {
          const int colg = ocol0 + ni * 16;
#pragma unroll
          for (int r = 0; r < 4; ++r) {
            const int rowg = orow0 + mi * 16 + r;
            ((float*)C)[(size_t)bz * sC + (size_t)rowg * ldc + colg] =
                acc[mi][ni][r] * linv[r];
          }
        }
      }
    }
  }  // pass loop
#undef STAGE
}

extern "C" void kernel_launch(void* const* d_in, const int* in_sizes, int n_in,
                              void* d_out, int out_size, void* d_ws, size_t ws_size,
                              hipStream_t stream) {
  const float* x = (const float*)d_in[0];
  const float* Wq = (const float*)d_in[1];
  const float* Wk = (const float*)d_in[2];
  const float* Wv = (const float*)d_in[3];
  float* out = (float*)d_out;
  char* ws = (char*)d_ws;

  u16* xb = (u16*)(ws + OFF_XB);
  u16* wT = (u16*)(ws + OFF_WQT);  // [WqT|WkT|WvT] contiguous: 3072 x 1024
  u16* qb = (u16*)(ws + OFF_Q);
  u16* kb = (u16*)(ws + OFF_K);
  u16* vt = (u16*)(ws + OFF_VT);
  u16* eb = (u16*)(ws + OFF_E);
  float* rsum = (float*)(ws + OFF_RS);

  // cast (8192 blocks) + W transpose (3072 blocks) + rs zeroing, one launch
  prep<<<8192 + 3072, 256, 0, stream>>>(x, xb, Wq, Wk, Wv, wT, rsum);

  // Fused QKV: 256^2 tiles, 64 by x 12 bx = 768 blocks (2/CU resident)
  qkv256<<<768, 512, 0, stream>>>(xb, wT, qb, kb, vt);

  // E = exp(scale·Q·K^T), causal, bf16; compact triangle grid; row sums -> rsum
  gemm128<2><<<576, 512, 0, stream>>>(
      qb, (size_t)SEQ * DIM, DIM, kb, (size_t)SEQ * DIM, DIM, eb, (size_t)SEQ * SEQ, SEQ,
      DIM, 0.03125f, rsum);

  // out = (E·V) / rsum via Vt; 256 uniform two-pass blocks (dispatch-order-proof)
  gemm128<3><<<256, 512, 0, stream>>>(
      eb, (size_t)SEQ * SEQ, SEQ, vt, (size_t)DIM * SEQ, SEQ, out, (size_t)SEQ * DIM, DIM,
      SEQ, 1.f, rsum);
}